// Round 5
// baseline (62.077 us; speedup 1.0000x reference)
//
#include <hip/hip_runtime.h>
#include <hip/hip_bf16.h>

// CrossAttentionOutLayer: out[b,i,j] = (1/H) * sum_c Q'[b,i,c] * K[b,j,c]
//   Q' = SCALE*(rna@Wq.T + bq) + rel_bias   (c = h*DK+d == flat rel_bias idx)
//   K  = prot@Wk.T + bk
// B=8 N=1024 M=1024 DIM2=1280 KIN=1344 H=8 DK=64 HDK=512 SCALE=0.125
//
// R5: proj LDS traffic halved — stage bf16 (reg-staged: global f32 -> reg ->
// cvt -> ds_write_b64) with double-buffered LDS, issue-early/write-late (T14).
// Loads pinned with sched_barrier(0) (R2's sink lesson; check VGPR~170).
// XOR swizzle mask3(r)=((r&3)<<1)|((r>>2)&1) applied to BOTH ds_write and
// ds_read 16B-chunk index (bank-conflict floor on both sides).

typedef __bf16 bf16x8 __attribute__((ext_vector_type(8)));
typedef __bf16 bf16x4 __attribute__((ext_vector_type(4)));
typedef float f32x4 __attribute__((ext_vector_type(4)));

__device__ inline bf16x4 cvt4(const f32x4 a) {
    bf16x4 r;
    r[0] = (__bf16)a[0]; r[1] = (__bf16)a[1];
    r[2] = (__bf16)a[2]; r[3] = (__bf16)a[3];
    return r;
}

// ---------------------------------------------------------------------------
// Fused Q+K projection. Tile 128x128, BK=64, 4 waves (2x2) of 64x64.
// bf16 double-buffered LDS (4x16KB = 64KB -> 2 blocks/CU).
// grid 512, bijective XCD swizzle.
// ---------------------------------------------------------------------------
__global__ __launch_bounds__(256, 2)
void proj_all(const float* __restrict__ rna,  const float* __restrict__ prot,
              const float* __restrict__ Wq,   const float* __restrict__ bq,
              const float* __restrict__ Wk,   const float* __restrict__ bk,
              const float* __restrict__ rb,
              __bf16* __restrict__ qout, __bf16* __restrict__ kout)
{
    __shared__ __bf16 AS[2][128 * 64];   // 2 x 16 KB
    __shared__ __bf16 WS[2][128 * 64];   // 2 x 16 KB

    const int bid = blockIdx.x;
    const int wg  = (bid & 7) * 64 + (bid >> 3);   // bijective XCD swizzle (512%8==0)
    const bool isQ = wg < 256;
    const int lwg  = isQ ? wg : wg - 256;
    const int brow = (lwg >> 2) * 128;
    const int bcol = (lwg & 3) * 128;

    const float* A    = isQ ? rna : prot;
    const float* W    = isQ ? Wq  : Wk;
    const float* bias = isQ ? bq  : bk;
    __bf16*      out  = isQ ? qout : kout;
    const int    K    = isQ ? 1280 : 1344;
    const int    nt   = K >> 6;          // 20 or 21 K-steps

    const int tid  = threadIdx.x;
    const int lane = tid & 63;
    const int wid  = tid >> 6;
    const int wr   = wid >> 1;
    const int wc   = wid & 1;
    const int fr   = lane & 15;
    const int q4   = lane >> 4;

    // ---- staging geometry: wave stages local rows [wid*32, wid*32+32) ----
    // inst i: lane -> row rloc + i*4, f32 col fr*4 (quarter-wave = 256B coalesced)
    const int rloc = wid * 32 + q4;
    const float* aGlob = A + (size_t)(brow + rloc) * K + fr * 4;
    const float* wGlob = W + (size_t)(bcol + rloc) * K + fr * 4;
    // LDS write (bf16 row = 128B = 8 chunks): chunk j = fr>>1, half = lane&1.
    // mask3(row) = (q4<<1)|(i&1)  ->  precompute even-i base, XOR 16 for odd i.
    const int lb = rloc * 128 + (((fr >> 1) ^ (q4 << 1)) << 4) + (lane & 1) * 8;

    // ---- fragment-read swizzle (row&7 = fr&7): rmask = ((fr&3)<<1)|((fr>>2)&1)
    const int rmask = ((fr & 3) << 1) | ((fr >> 2) & 1);

    f32x4 acc[4][4] = {};
    f32x4 ra[8], rw[8];

    #pragma unroll
    for (int i = 0; i < 8; ++i) {
        ra[i] = *(const f32x4*)(aGlob + (size_t)(i * 4) * K);
        rw[i] = *(const f32x4*)(wGlob + (size_t)(i * 4) * K);
    }

    for (int t = 0; t < nt; ++t) {
        char* as = (char*)AS[t & 1];
        char* ws = (char*)WS[t & 1];
        __syncthreads();                     // readers of this buf (iter t-2) done
        #pragma unroll
        for (int i = 0; i < 8; ++i) {
            *(bf16x4*)(as + ((lb ^ ((i & 1) << 4)) + i * 512)) = cvt4(ra[i]);
            *(bf16x4*)(ws + ((lb ^ ((i & 1) << 4)) + i * 512)) = cvt4(rw[i]);
        }
        if (t + 1 < nt) {                    // issue next step's loads NOW;
            const int k0n = (t + 1) * 64;    // they land during this step's MFMA
            #pragma unroll
            for (int i = 0; i < 8; ++i) {
                ra[i] = *(const f32x4*)(aGlob + (size_t)(i * 4) * K + k0n);
                rw[i] = *(const f32x4*)(wGlob + (size_t)(i * 4) * K + k0n);
            }
        }
        __builtin_amdgcn_sched_barrier(0);   // pin load issuance here (anti-sink)
        __syncthreads();                     // buf[t&1] ready

        #pragma unroll
        for (int kk = 0; kk < 2; ++kk) {
            bf16x8 af[4], bw[4];
            #pragma unroll
            for (int m = 0; m < 4; ++m)
                af[m] = *(const bf16x8*)(as + (wr * 64 + m * 16 + fr) * 128
                                            + (((kk * 4 + q4) ^ rmask) << 4));
            #pragma unroll
            for (int n = 0; n < 4; ++n)
                bw[n] = *(const bf16x8*)(ws + (wc * 64 + n * 16 + fr) * 128
                                            + (((kk * 4 + q4) ^ rmask) << 4));
            #pragma unroll
            for (int m = 0; m < 4; ++m)
                #pragma unroll
                for (int n = 0; n < 4; ++n)
                    acc[m][n] = __builtin_amdgcn_mfma_f32_16x16x32_bf16(af[m], bw[n], acc[m][n], 0, 0, 0);
        }
    }

    // C/D layout: col = lane&15, row = (lane>>4)*4 + j  [m89-verified]
    const int r0 = (lane >> 4) * 4;
    #pragma unroll
    for (int n = 0; n < 4; ++n) {
        const int c = bcol + wc * 64 + n * 16 + fr;
        const float bv = bias[c];
        const float rv = isQ ? rb[c] : 0.0f;
        #pragma unroll
        for (int m = 0; m < 4; ++m) {
            const int row = brow + wr * 64 + m * 16 + r0;
            #pragma unroll
            for (int j = 0; j < 4; ++j) {
                float v = acc[m][n][j] + bv;
                if (isQ) v = 0.125f * v + rv;
                out[(size_t)(row + j) * 512 + c] = (__bf16)v;
            }
        }
    }
}

// ---------------------------------------------------------------------------
// Batched GEMM: out[b,i,j] = 0.125 * sum_c Q[b,i,c]*K[b,j,c]
// 128x128 tile, BK=64, gload_lds staging, swizzled bf16 LDS. (~HBM write floor)
// ---------------------------------------------------------------------------
__global__ __launch_bounds__(256, 2)
void attn_kernel(const __bf16* __restrict__ Q,
                 const __bf16* __restrict__ Kb,
                 float* __restrict__ out)
{
    __shared__ __bf16 As[128 * 64];   // 16 KB, linear dest (swizzled content)
    __shared__ __bf16 Bs[128 * 64];

    const int tid  = threadIdx.x;
    const int lane = tid & 63;
    const int wid  = tid >> 6;
    const int wr   = wid >> 1;
    const int wc   = wid & 1;
    const int b    = blockIdx.z;
    const int brow = blockIdx.y * 128;
    const int bcol = blockIdx.x * 128;

    const __bf16* Qb = Q  + (size_t)b * 1024 * 512;
    const __bf16* Kp = Kb + (size_t)b * 1024 * 512;

    const int fr = lane & 15;
    const int q4 = lane >> 4;

    f32x4 acc[4][4] = {};

    const int lr3 = lane >> 3;
    const int m3  = ((lr3 & 3) << 1) | ((lr3 >> 2) & 1);
    const int scol = ((lane & 7) ^ m3) * 8;            // swizzled global bf16 col
    const int rmask = ((fr & 3) << 1) | ((fr >> 2) & 1);

    for (int k0 = 0; k0 < 512; k0 += 64) {
        __syncthreads();
        #pragma unroll
        for (int i = 0; i < 4; ++i) {
            const int rbase = wid * 32 + i * 8;
            const __bf16* sa = Qb + (size_t)(brow + rbase + lr3) * 512 + k0 + scol;
            const __bf16* sb = Kp + (size_t)(bcol + rbase + lr3) * 512 + k0 + scol;
            __builtin_amdgcn_global_load_lds(
                (const __attribute__((address_space(1))) void*)sa,
                (__attribute__((address_space(3))) void*)&As[rbase * 64], 16, 0, 0);
            __builtin_amdgcn_global_load_lds(
                (const __attribute__((address_space(1))) void*)sb,
                (__attribute__((address_space(3))) void*)&Bs[rbase * 64], 16, 0, 0);
        }
        __syncthreads();

        #pragma unroll
        for (int kk = 0; kk < 2; ++kk) {
            const int ci = kk * 4 + q4;
            bf16x8 af[4], bf_[4];
            #pragma unroll
            for (int m = 0; m < 4; ++m)
                af[m] = *(const bf16x8*)(&As[(wr * 64 + m * 16 + fr) * 64 + ((ci ^ rmask) << 3)]);
            #pragma unroll
            for (int n = 0; n < 4; ++n)
                bf_[n] = *(const bf16x8*)(&Bs[(wc * 64 + n * 16 + fr) * 64 + ((ci ^ rmask) << 3)]);
            #pragma unroll
            for (int m = 0; m < 4; ++m)
                #pragma unroll
                for (int n = 0; n < 4; ++n)
                    acc[m][n] = __builtin_amdgcn_mfma_f32_16x16x32_bf16(af[m], bf_[n], acc[m][n], 0, 0, 0);
        }
    }

    float* op = out + (size_t)b * 1024 * 1024;
    const int r0 = (lane >> 4) * 4;
    #pragma unroll
    for (int n = 0; n < 4; ++n) {
        const int col = bcol + wc * 64 + n * 16 + fr;
        #pragma unroll
        for (int m = 0; m < 4; ++m) {
            const int row = brow + wr * 64 + m * 16 + r0;
            #pragma unroll
            for (int j = 0; j < 4; ++j)
                op[(size_t)(row + j) * 1024 + col] = 0.125f * acc[m][n][j];
        }
    }
}

extern "C" void kernel_launch(void* const* d_in, const int* in_sizes, int n_in,
                              void* d_out, int out_size, void* d_ws, size_t ws_size,
                              hipStream_t stream) {
    const float* rna  = (const float*)d_in[0];  // [8,1024,1280]
    const float* prot = (const float*)d_in[1];  // [8,1024,1344]
    const float* Wq   = (const float*)d_in[2];  // [512,1280]
    const float* bq   = (const float*)d_in[3];  // [512]
    const float* Wk   = (const float*)d_in[4];  // [512,1344]
    const float* bk   = (const float*)d_in[5];  // [512]
    const float* rb   = (const float*)d_in[6];  // [512] (flat idx == channel)

    __bf16* qws = (__bf16*)d_ws;                // [8192, 512] bf16 = 8 MB
    __bf16* kws = qws + (size_t)8192 * 512;     // [8192, 512] bf16 = 8 MB

    proj_all<<<dim3(512), dim3(256), 0, stream>>>(rna, prot, Wq, bq, Wk, bk, rb, qws, kws);
    attn_kernel<<<dim3(8, 8, 8), dim3(256), 0, stream>>>(qws, kws, (float*)d_out);
}

// Round 6
// 58.120 us; speedup vs baseline: 1.0681x; 1.0681x over previous
//
#include <hip/hip_runtime.h>
#include <hip/hip_bf16.h>

// CrossAttentionOutLayer: out[b,i,j] = (1/H) * sum_c Q'[b,i,c] * K[b,j,c]
//   Q' = SCALE*(rna@Wq.T + bq) + rel_bias   (c = h*DK+d == flat rel_bias idx)
//   K  = prot@Wk.T + bk
// B=8 N=1024 M=1024 DIM2=1280 KIN=1344 H=8 DK=64 HDK=512 SCALE=0.125
//
// R6: pin the staging pipeline. R5's plain-load prefetch was sunk (VGPR=92).
// Loads are now inline-asm global_load_dwordx4 (unsinkable); waits are
// explicit asm s_waitcnt; barrier is raw s_barrier (no vmcnt drain) with
// explicit lgkmcnt(0); sched_barrier(0) after vmcnt wait per rule #18.
// Single barrier per K-step (dbuf: write(t+1) parity != compute(t) parity).

typedef __bf16 bf16x8 __attribute__((ext_vector_type(8)));
typedef __bf16 bf16x4 __attribute__((ext_vector_type(4)));
typedef float f32x4 __attribute__((ext_vector_type(4)));

__device__ inline bf16x4 cvt4(const f32x4 a) {
    bf16x4 r;
    r[0] = (__bf16)a[0]; r[1] = (__bf16)a[1];
    r[2] = (__bf16)a[2]; r[3] = (__bf16)a[3];
    return r;
}

// unsinkable 16B global load: compiler sees an opaque asm defining dst.
// NO implicit wait is generated -- caller MUST s_waitcnt vmcnt before reading dst.
__device__ inline void gload4(f32x4& dst, const float* p) {
    asm volatile("global_load_dwordx4 %0, %1, off"
                 : "=v"(dst) : "v"(p) : "memory");
}

// ---------------------------------------------------------------------------
// Fused Q+K projection. Tile 128x128, BK=64, 4 waves (2x2) of 64x64.
// bf16 double-buffered LDS (64KB -> 2 blocks/CU). grid 512, XCD swizzle.
// ---------------------------------------------------------------------------
__global__ __launch_bounds__(256, 2)
void proj_all(const float* __restrict__ rna,  const float* __restrict__ prot,
              const float* __restrict__ Wq,   const float* __restrict__ bq,
              const float* __restrict__ Wk,   const float* __restrict__ bk,
              const float* __restrict__ rb,
              __bf16* __restrict__ qout, __bf16* __restrict__ kout)
{
    __shared__ __bf16 AS[2][128 * 64];   // 2 x 16 KB
    __shared__ __bf16 WS[2][128 * 64];   // 2 x 16 KB

    const int bid = blockIdx.x;
    const int wg  = (bid & 7) * 64 + (bid >> 3);   // bijective XCD swizzle (512%8==0)
    const bool isQ = wg < 256;
    const int lwg  = isQ ? wg : wg - 256;
    const int brow = (lwg >> 2) * 128;
    const int bcol = (lwg & 3) * 128;

    const float* A    = isQ ? rna : prot;
    const float* W    = isQ ? Wq  : Wk;
    const float* bias = isQ ? bq  : bk;
    __bf16*      out  = isQ ? qout : kout;
    const int    K    = isQ ? 1280 : 1344;
    const int    nt   = K >> 6;          // 20 or 21 K-steps

    const int tid  = threadIdx.x;
    const int lane = tid & 63;
    const int wid  = tid >> 6;
    const int wr   = wid >> 1;
    const int wc   = wid & 1;
    const int fr   = lane & 15;
    const int q4   = lane >> 4;

    // staging: wave stages local rows [wid*32, wid*32+32); inst i: row rloc+i*4,
    // f32 col fr*4 (quarter-wave = 256B fully coalesced).
    const int rloc = wid * 32 + q4;
    const float* aGlob = A + (size_t)(brow + rloc) * K + fr * 4;
    const float* wGlob = W + (size_t)(bcol + rloc) * K + fr * 4;
    // LDS write addr (bf16 row = 128B = 8 x 16B chunks), swizzle
    // mask3(row) = ((row&3)<<1)|((row>>2)&1); row&7 = q4 + 4*(i&1)
    //   -> base applies (fr>>1)^(q4<<1), inst i XORs chunk bit0 (i&1).
    const int lb = rloc * 128 + (((fr >> 1) ^ (q4 << 1)) << 4) + (lane & 1) * 8;
    // fragment-read swizzle (frag row&7 = fr&7):
    const int rmask = ((fr & 3) << 1) | ((fr >> 2) & 1);

    f32x4 acc[4][4] = {};
    f32x4 ra[8], rw[8];

    // prologue: issue tile-0 loads
    #pragma unroll
    for (int i = 0; i < 8; ++i) {
        gload4(ra[i], aGlob + (size_t)(i * 4) * K);
        gload4(rw[i], wGlob + (size_t)(i * 4) * K);
    }

    for (int t = 0; t < nt; ++t) {
        char* as = (char*)AS[t & 1];
        char* ws = (char*)WS[t & 1];

        // tile-t regs arrived (loads issued one full compute phase ago)
        asm volatile("s_waitcnt vmcnt(0)" ::: "memory");
        __builtin_amdgcn_sched_barrier(0);   // rule #18: cvt reads must not hoist

        #pragma unroll
        for (int i = 0; i < 8; ++i) {
            *(bf16x4*)(as + ((lb ^ ((i & 1) << 4)) + i * 512)) = cvt4(ra[i]);
            *(bf16x4*)(ws + ((lb ^ ((i & 1) << 4)) + i * 512)) = cvt4(rw[i]);
        }

        if (t + 1 < nt) {                    // issue tile t+1; rides vmcnt queue
            const int k0n = (t + 1) * 64;    // across the barrier (counted, never
            #pragma unroll                   // drained mid-loop)
            for (int i = 0; i < 8; ++i) {
                gload4(ra[i], aGlob + (size_t)(i * 4) * K + k0n);
                gload4(rw[i], wGlob + (size_t)(i * 4) * K + k0n);
            }
        }
        __builtin_amdgcn_sched_barrier(0);
        asm volatile("s_waitcnt lgkmcnt(0)" ::: "memory");  // ds_writes visible
        __builtin_amdgcn_s_barrier();        // raw: does NOT drain vmcnt
        __builtin_amdgcn_sched_barrier(0);

        #pragma unroll
        for (int kk = 0; kk < 2; ++kk) {
            bf16x8 af[4], bw[4];
            #pragma unroll
            for (int m = 0; m < 4; ++m)
                af[m] = *(const bf16x8*)(as + (wr * 64 + m * 16 + fr) * 128
                                            + (((kk * 4 + q4) ^ rmask) << 4));
            #pragma unroll
            for (int n = 0; n < 4; ++n)
                bw[n] = *(const bf16x8*)(ws + (wc * 64 + n * 16 + fr) * 128
                                            + (((kk * 4 + q4) ^ rmask) << 4));
            #pragma unroll
            for (int m = 0; m < 4; ++m)
                #pragma unroll
                for (int n = 0; n < 4; ++n)
                    acc[m][n] = __builtin_amdgcn_mfma_f32_16x16x32_bf16(af[m], bw[n], acc[m][n], 0, 0, 0);
        }
    }

    // C/D layout: col = lane&15, row = (lane>>4)*4 + j  [m89-verified]
    const int r0 = (lane >> 4) * 4;
    #pragma unroll
    for (int n = 0; n < 4; ++n) {
        const int c = bcol + wc * 64 + n * 16 + fr;
        const float bv = bias[c];
        const float rv = isQ ? rb[c] : 0.0f;
        #pragma unroll
        for (int m = 0; m < 4; ++m) {
            const int row = brow + wr * 64 + m * 16 + r0;
            #pragma unroll
            for (int j = 0; j < 4; ++j) {
                float v = acc[m][n][j] + bv;
                if (isQ) v = 0.125f * v + rv;
                out[(size_t)(row + j) * 512 + c] = (__bf16)v;
            }
        }
    }
}

// ---------------------------------------------------------------------------
// Batched GEMM: out[b,i,j] = 0.125 * sum_c Q[b,i,c]*K[b,j,c]
// 128x128 tile, BK=64, gload_lds staging, swizzled bf16 LDS. (unchanged R5)
// ---------------------------------------------------------------------------
__global__ __launch_bounds__(256, 2)
void attn_kernel(const __bf16* __restrict__ Q,
                 const __bf16* __restrict__ Kb,
                 float* __restrict__ out)
{
    __shared__ __bf16 As[128 * 64];   // 16 KB, linear dest (swizzled content)
    __shared__ __bf16 Bs[128 * 64];

    const int tid  = threadIdx.x;
    const int lane = tid & 63;
    const int wid  = tid >> 6;
    const int wr   = wid >> 1;
    const int wc   = wid & 1;
    const int b    = blockIdx.z;
    const int brow = blockIdx.y * 128;
    const int bcol = blockIdx.x * 128;

    const __bf16* Qb = Q  + (size_t)b * 1024 * 512;
    const __bf16* Kp = Kb + (size_t)b * 1024 * 512;

    const int fr = lane & 15;
    const int q4 = lane >> 4;

    f32x4 acc[4][4] = {};

    const int lr3 = lane >> 3;
    const int m3  = ((lr3 & 3) << 1) | ((lr3 >> 2) & 1);
    const int scol = ((lane & 7) ^ m3) * 8;            // swizzled global bf16 col
    const int rmask = ((fr & 3) << 1) | ((fr >> 2) & 1);

    for (int k0 = 0; k0 < 512; k0 += 64) {
        __syncthreads();
        #pragma unroll
        for (int i = 0; i < 4; ++i) {
            const int rbase = wid * 32 + i * 8;
            const __bf16* sa = Qb + (size_t)(brow + rbase + lr3) * 512 + k0 + scol;
            const __bf16* sb = Kp + (size_t)(bcol + rbase + lr3) * 512 + k0 + scol;
            __builtin_amdgcn_global_load_lds(
                (const __attribute__((address_space(1))) void*)sa,
                (__attribute__((address_space(3))) void*)&As[rbase * 64], 16, 0, 0);
            __builtin_amdgcn_global_load_lds(
                (const __attribute__((address_space(1))) void*)sb,
                (__attribute__((address_space(3))) void*)&Bs[rbase * 64], 16, 0, 0);
        }
        __syncthreads();

        #pragma unroll
        for (int kk = 0; kk < 2; ++kk) {
            const int ci = kk * 4 + q4;
            bf16x8 af[4], bf_[4];
            #pragma unroll
            for (int m = 0; m < 4; ++m)
                af[m] = *(const bf16x8*)(&As[(wr * 64 + m * 16 + fr) * 64 + ((ci ^ rmask) << 3)]);
            #pragma unroll
            for (int n = 0; n < 4; ++n)
                bf_[n] = *(const bf16x8*)(&Bs[(wc * 64 + n * 16 + fr) * 64 + ((ci ^ rmask) << 3)]);
            #pragma unroll
            for (int m = 0; m < 4; ++m)
                #pragma unroll
                for (int n = 0; n < 4; ++n)
                    acc[m][n] = __builtin_amdgcn_mfma_f32_16x16x32_bf16(af[m], bf_[n], acc[m][n], 0, 0, 0);
        }
    }

    float* op = out + (size_t)b * 1024 * 1024;
    const int r0 = (lane >> 4) * 4;
    #pragma unroll
    for (int n = 0; n < 4; ++n) {
        const int col = bcol + wc * 64 + n * 16 + fr;
        #pragma unroll
        for (int m = 0; m < 4; ++m) {
            const int row = brow + wr * 64 + m * 16 + r0;
            #pragma unroll
            for (int j = 0; j < 4; ++j)
                op[(size_t)(row + j) * 1024 + col] = 0.125f * acc[m][n][j];
        }
    }
}

extern "C" void kernel_launch(void* const* d_in, const int* in_sizes, int n_in,
                              void* d_out, int out_size, void* d_ws, size_t ws_size,
                              hipStream_t stream) {
    const float* rna  = (const float*)d_in[0];  // [8,1024,1280]
    const float* prot = (const float*)d_in[1];  // [8,1024,1344]
    const float* Wq   = (const float*)d_in[2];  // [512,1280]
    const float* bq   = (const float*)d_in[3];  // [512]
    const float* Wk   = (const float*)d_in[4];  // [512,1344]
    const float* bk   = (const float*)d_in[5];  // [512]
    const float* rb   = (const float*)d_in[6];  // [512] (flat idx == channel)

    __bf16* qws = (__bf16*)d_ws;                // [8192, 512] bf16 = 8 MB
    __bf16* kws = qws + (size_t)8192 * 512;     // [8192, 512] bf16 = 8 MB

    proj_all<<<dim3(512), dim3(256), 0, stream>>>(rna, prot, Wq, bq, Wk, bk, rb, qws, kws);
    attn_kernel<<<dim3(8, 8, 8), dim3(256), 0, stream>>>(qws, kws, (float*)d_out);
}